// Round 2
// baseline (362.786 us; speedup 1.0000x reference)
//
#include <hip/hip_runtime.h>

namespace {

constexpr int D  = 64;    // channels per head
constexpr int T  = 2048;  // sequence length
constexpr int TQ = 64;    // queries per block
constexpr int NT = T / 64;
constexpr float SCL = 0.125f * 1.44269504088896340736f;  // scale^2 * log2(e)

// workspace layout (units: unsigned short): KV tiles only: (h*32+kt)*8192
//   K: first 4096 shorts, [s][c] rows of 64, granule-swizzled (quarter w = s rows 16w..16w+16 = contiguous 2 KB)
//   V: next 4096 shorts, QUARTER-BLOCKED: quarter wq (2 KB) = rows c of 16 s, granules of 4 shorts swizzled g^((c>>2)&3)
// Q is NOT staged: attn_main transposes it in-LDS from fp32 directly.
constexpr size_t WS_NEED = (size_t)64 * 32 * 8192 * 2;   // 33554432 B

typedef __bf16 bf16x8 __attribute__((ext_vector_type(8)));
typedef float  f32x4  __attribute__((ext_vector_type(4)));
typedef unsigned short u16x4 __attribute__((ext_vector_type(4)));
typedef unsigned short u16x8 __attribute__((ext_vector_type(8)));
typedef unsigned int   u32x2 __attribute__((ext_vector_type(2)));
typedef short          s16x4 __attribute__((ext_vector_type(4)));

__device__ inline unsigned short f2bf(float f) {   // RNE fp32->bf16, finite inputs
    unsigned int u = __builtin_bit_cast(unsigned int, f);
    u += 0x7FFFu + ((u >> 16) & 1u);
    return (unsigned short)(u >> 16);
}

__device__ inline unsigned int pkbf(float a, float b) {
#if __has_builtin(__builtin_amdgcn_cvt_pk_bf16_f32)
    auto r = __builtin_amdgcn_cvt_pk_bf16_f32(a, b);
    static_assert(sizeof(r) == 4, "cvt_pk_bf16 size");
    return __builtin_bit_cast(unsigned int, r);
#else
    return (unsigned int)f2bf(a) | ((unsigned int)f2bf(b) << 16);
#endif
}

// 64-short rows, 16B granules XOR-swizzled by ((row>>1)&7) (K/Q images).
__device__ inline int frag_off(int row, int c0) {
    int g = (c0 >> 3) ^ ((row >> 1) & 7);
    return row * 64 + g * 8;
}

__device__ inline void async_cp16(const void* g, void* l) {
    __builtin_amdgcn_global_load_lds(
        (const __attribute__((address_space(1))) unsigned int*)g,
        (__attribute__((address_space(3))) unsigned int*)l, 16, 0, 0);
}

// ---------------- pre-pass: K,V fp32 -> bf16 swizzled tiles ------------------
__global__ __launch_bounds__(256)
void prepass(const float* __restrict__ qkv, unsigned short* __restrict__ ws) {
    const int tile = blockIdx.x, h = blockIdx.y, zz = blockIdx.z;  // zz: 0=K, 1=V
    const int tid = threadIdx.x;
    const float* src = qkv + (size_t)h * 3 * D * T + (size_t)(zz + 1) * D * T + tile * 64;
    __shared__ unsigned short L[4096];

    if (zz == 1) {  // V: quarter-blocked [wq][c][16s], granule(4sh) swizzle g^((c>>2)&3)
        unsigned short* dst = ws + (size_t)(h * 32 + tile) * 8192 + 4096;
        const int c = tid >> 2, g = tid & 3;
        const int sg = g ^ ((c >> 2) & 3);           // source granule (s-local/4)
        #pragma unroll
        for (int wq = 0; wq < 4; wq++) {
            f32x4 a = *(const f32x4*)(src + (size_t)c * T + wq * 16 + sg * 4);
            u16x4 wv = { f2bf(a[0]), f2bf(a[1]), f2bf(a[2]), f2bf(a[3]) };
            *(u16x4*)(dst + wq * 1024 + tid * 4) = wv;   // coalesced 8B stores
        }
    } else {       // K: transpose [c][t] -> swizzled [t][c] via LDS
        const int c0 = (tid >> 4) * 4, s4 = tid & 15;
        float fr[4][4];
        #pragma unroll
        for (int r = 0; r < 4; r++)
            *(f32x4*)fr[r] = *(const f32x4*)(src + (size_t)(c0 + r) * T + s4 * 4);
        #pragma unroll
        for (int j = 0; j < 4; j++) {
            int trow = s4 * 4 + j;
            u16x4 wv = { f2bf(fr[0][j]), f2bf(fr[1][j]),
                         f2bf(fr[2][j]), f2bf(fr[3][j]) };
            *(u16x4*)(L + frag_off(trow, c0) + (c0 & 7)) = wv;
        }
        __syncthreads();
        unsigned short* dst = ws + (size_t)(h * 32 + tile) * 8192;
        #pragma unroll
        for (int i = 0; i < 2; i++)
            *(u16x8*)(dst + tid * 16 + i * 8) = *(const u16x8*)(L + tid * 16 + i * 8);
    }
}

// ---------------- main: barrier-free-loop flash attention --------------------
// Block = 4 waves; wave w owns s-quarter [16w,16w+16), all 64 t.
// TRI-BUFFERED staging ring (3 x 4KB per wave), stage distance 2:
//   body KT: lgkmcnt(0) WAR guard -> STAGE(KT+2 -> buf (KT+2)%3) ->
//   vmcnt(8): tile KT (issued 2 bodies ago, ~700 cyc) landed ->
//   in-body ds_reads from buf KT%3 -> compute. No persistent reg fragments
//   (R1's reg-dbuf spilled: WRITE_SIZE 45->117MB). Q transposed in-LDS in
//   the prologue into the buf2 regions (dead until body 0 stages tile 2).

#define STAGE(J, B)                                                          \
  { const char* g = kvb + (size_t)(J) * 16384;                               \
    char* lk = wbase + (B) * 4096;                                           \
    async_cp16(g,               lk);                                         \
    async_cp16(g + 1024,        lk + 1024);                                  \
    async_cp16(g + 8192,        lk + 2048);                                  \
    async_cp16(g + 8192 + 1024, lk + 3072); }

#define BODY(KT, B, SB, DO_STAGE, WAITIMM)                                   \
  {                                                                          \
    __builtin_amdgcn_s_waitcnt(0xC07F);  /* lgkmcnt(0): WAR guard */         \
    if (DO_STAGE) STAGE((KT) + 2, SB)                                        \
    __builtin_amdgcn_s_waitcnt(WAITIMM); /* vmcnt(N): tile KT landed */      \
    bf16x8 aK0 = *(const bf16x8*)(aK0p + (B) * 4096);                        \
    bf16x8 aK1 = *(const bf16x8*)(aK1p + (B) * 4096);                        \
    s16x4 aV0 = *(const s16x4*)(aVp + (B) * 4096);                           \
    s16x4 aV1 = *(const s16x4*)(aVp + (B) * 4096 + 512);                     \
    s16x4 aV2 = *(const s16x4*)(aVp + (B) * 4096 + 1024);                    \
    s16x4 aV3 = *(const s16x4*)(aVp + (B) * 4096 + 1536);                    \
    f32x4 acc_s[4];                                                          \
    _Pragma("unroll")                                                        \
    for (int ti = 0; ti < 4; ti++)                                           \
      acc_s[ti] = __builtin_amdgcn_mfma_f32_16x16x32_bf16(                   \
          aK0, bQ[ti][0], ZF, 0, 0, 0);                                      \
    _Pragma("unroll")                                                        \
    for (int ti = 0; ti < 4; ti++)                                           \
      acc_s[ti] = __builtin_amdgcn_mfma_f32_16x16x32_bf16(                   \
          aK1, bQ[ti][1], acc_s[ti], 0, 0, 0);                               \
    s16x4 bP[4];                                                             \
    _Pragma("unroll")                                                        \
    for (int ti = 0; ti < 4; ti++) {                                         \
      float p0 = __builtin_amdgcn_exp2f(acc_s[ti][0]);                       \
      float p1 = __builtin_amdgcn_exp2f(acc_s[ti][1]);                       \
      float p2 = __builtin_amdgcn_exp2f(acc_s[ti][2]);                       \
      float p3 = __builtin_amdgcn_exp2f(acc_s[ti][3]);                       \
      l_acc[ti] += (p0 + p1) + (p2 + p3);                                    \
      u32x2 pk = { pkbf(p0, p1), pkbf(p2, p3) };                             \
      bP[ti] = __builtin_bit_cast(s16x4, pk);                                \
    }                                                                        \
    _Pragma("unroll")                                                        \
    for (int ti = 0; ti < 4; ti++) {                                         \
      acc_o[0][ti] = __builtin_amdgcn_mfma_f32_16x16x16bf16_1k(              \
          aV0, bP[ti], acc_o[0][ti], 0, 0, 0);                               \
      acc_o[1][ti] = __builtin_amdgcn_mfma_f32_16x16x16bf16_1k(              \
          aV1, bP[ti], acc_o[1][ti], 0, 0, 0);                               \
      acc_o[2][ti] = __builtin_amdgcn_mfma_f32_16x16x16bf16_1k(              \
          aV2, bP[ti], acc_o[2][ti], 0, 0, 0);                               \
      acc_o[3][ti] = __builtin_amdgcn_mfma_f32_16x16x16bf16_1k(              \
          aV3, bP[ti], acc_o[3][ti], 0, 0, 0);                               \
    }                                                                        \
  }

__global__ __launch_bounds__(256, 3)
void attn_main(const unsigned short* __restrict__ ws,
               const float* __restrict__ qkv, float* __restrict__ out) {
    const int h  = blockIdx.x;      // head pinned to XCD h%8 for L2 locality
    const int qt = blockIdx.y;
    const int t0 = qt * TQ;
    const int tid  = threadIdx.x;
    const int lane = tid & 63;
    const int w    = tid >> 6;      // wave id = s-quarter
    const int ln   = lane & 15, q4 = lane >> 4;

    __shared__ char sbuf[49152];    // 4 waves x 3 x 4KB staging ring; merge scratch
    char* wbase = sbuf + w * 12288;
    unsigned short* S16 = (unsigned short*)sbuf;

    // ---- prologue: fp32 Q loads + early KV staging ----
    const float* qsrc = qkv + (size_t)h * 3 * D * T + t0;
    const int c0 = (tid >> 4) * 4, s4 = tid & 15;
    float fr[4][4];
    #pragma unroll
    for (int r = 0; r < 4; r++)
        *(f32x4*)fr[r] = *(const f32x4*)(qsrc + (size_t)(c0 + r) * T + s4 * 4);

    const char* kvb = (const char*)ws + (size_t)(h * 32) * 16384
                      + (size_t)w * 2048 + lane * 16;
    STAGE(0, 0)                      // tiles 0,1 -> bufs 0,1 (async, overlap Q)
    STAGE(1, 1)

    // Q -> bf16 swizzled image in the 4 buf2 regions (wave ti's wbase+8192),
    // chunk ti (1024 shorts) = rows t in [16*ti, 16*ti+16). Same row swizzle as K.
    #pragma unroll
    for (int j = 0; j < 4; j++) {
        int trow = s4 * 4 + j;
        int g = (c0 >> 3) ^ ((trow >> 1) & 7);
        u16x4 wv = { f2bf(fr[0][j] * SCL), f2bf(fr[1][j] * SCL),
                     f2bf(fr[2][j] * SCL), f2bf(fr[3][j] * SCL) };
        *(u16x4*)(S16 + (trow >> 4) * 6144 + 4096 + (trow & 15) * 64 + g * 8 + (c0 & 7)) = wv;
    }
    __syncthreads();                 // Q image visible; tiles 0,1 drained (vmcnt0)
    bf16x8 bQ[4][2];
    #pragma unroll
    for (int ti = 0; ti < 4; ti++)
        #pragma unroll
        for (int kc = 0; kc < 2; kc++) {
            int cc = kc * 32 + q4 * 8;
            int g = (cc >> 3) ^ ((ln >> 1) & 7);
            bQ[ti][kc] = *(const bf16x8*)(S16 + ti * 6144 + 4096 + ln * 64 + g * 8);
        }
    __syncthreads();                 // frags read everywhere; buf2 regions reusable

    // fragment base addresses within this wave's buf0 ((B)*4096 folds into imm)
    const char* aK0p = wbase + 2 * frag_off(ln, q4 * 8);
    const char* aK1p = wbase + 2 * frag_off(ln, 32 + q4 * 8);
    const int   vsw  = (q4 ^ ((ln >> 2) & 3)) * 4;  // V granule swizzle (ci-invariant)
    const char* aVp  = wbase + 2048 + 32 * ln + 2 * vsw;  // +512*ci per channel group

    const f32x4 ZF = {0.f, 0.f, 0.f, 0.f};
    f32x4 acc_o[4][4];   // [ci][ti], partial over this wave's s-quarter
    #pragma unroll
    for (int ci = 0; ci < 4; ci++)
        #pragma unroll
        for (int ti = 0; ti < 4; ti++) acc_o[ci][ti] = ZF;
    float l_acc[4] = {0.f, 0.f, 0.f, 0.f};

    // steady state: 3 tiles (12 cps) in flight; vmcnt(8) waits for the tile
    // staged TWO bodies ago. Tail: vmcnt(4) then vmcnt(0).
    #pragma unroll 1
    for (int m = 0; m < 10; m++) {   // kt = 0..29
        BODY(3 * m,     0, 2, 1, 0x0F78)   // stage kt+2 -> buf2, vmcnt(8)
        BODY(3 * m + 1, 1, 0, 1, 0x0F78)   // stage kt+3 -> buf0
        BODY(3 * m + 2, 2, 1, 1, 0x0F78)   // stage kt+4 -> buf1
    }
    BODY(30, 0, 0, 0, 0x0F74)        // no stage; vmcnt(4): tile 30 landed
    BODY(31, 1, 0, 0, 0x0F70)        // vmcnt(0): tile 31 landed

    // ---- epilogue: XOR-butterfly merge of 4 s-quarter partials ----
    float lv[4];
    #pragma unroll
    for (int ti = 0; ti < 4; ti++) { // l: reduce over q4, keep in regs
        float s = l_acc[ti];
        s += __shfl_xor(s, 16, 64);
        s += __shfl_xor(s, 32, 64);
        lv[ti] = s;
    }
    __syncthreads();                 // first barrier since prologue
    float* slots = (float*)sbuf;     // region[w] = 8 KB (2048 floats)
    // round 1: exchange with w^1 on bit0
    #pragma unroll
    for (int q = 0; q < 4; q++)
        if ((q ^ w) & 1) {
            float* dst = slots + w * 2048 + (q >> 1) * 1024;
            #pragma unroll
            for (int ti = 0; ti < 4; ti++)
                *(f32x4*)(dst + ti * 256 + lane * 4) = acc_o[q][ti];
        }
    __syncthreads();
    #pragma unroll
    for (int q = 0; q < 4; q++)
        if (!((q ^ w) & 1)) {
            const float* srcp = slots + (w ^ 1) * 2048 + (q >> 1) * 1024;
            #pragma unroll
            for (int ti = 0; ti < 4; ti++)
                acc_o[q][ti] += *(const f32x4*)(srcp + ti * 256 + lane * 4);
        }
    __syncthreads();
    // round 2: exchange with w^2 on bit1 (lower 4KB of region); publish l into
    // the now-unused upper half (region[w] + 1024 floats).
    #pragma unroll
    for (int q = 0; q < 4; q++)
        if (((q ^ w) & 3) == 2) {
            float* dst = slots + w * 2048;
            #pragma unroll
            for (int ti = 0; ti < 4; ti++)
                *(f32x4*)(dst + ti * 256 + lane * 4) = acc_o[q][ti];
        }
    if (q4 == 0) {
        #pragma unroll
        for (int ti = 0; ti < 4; ti++)
            slots[w * 2048 + 1024 + ti * 16 + ln] = lv[ti];
    }
    __syncthreads();
    #pragma unroll
    for (int q = 0; q < 4; q++)
        if (q == w) {
            const float* srcp = slots + (w ^ 2) * 2048;
            float linv[4];
            #pragma unroll
            for (int ti = 0; ti < 4; ti++) {
                int tt = ti * 16 + ln;
                linv[ti] = 1.0f / (slots[1024 + tt] + slots[2048 + 1024 + tt] +
                                   slots[4096 + 1024 + tt] + slots[6144 + 1024 + tt]);
                acc_o[q][ti] += *(const f32x4*)(srcp + ti * 256 + lane * 4);
            }
            float* ob = out + (size_t)h * D * T + t0;
            #pragma unroll
            for (int ti = 0; ti < 4; ti++)
                #pragma unroll
                for (int rr = 0; rr < 4; rr++) {
                    int c = 16 * w + q4 * 4 + rr;
                    ob[(size_t)c * T + ti * 16 + ln] = acc_o[q][ti][rr] * linv[ti];
                }
        }
}

// ---------------- fallback (R2 kernel, proven): used if ws too small ----------
__device__ inline bf16x8 frag8(const unsigned short* p, int row, int c0) {
    return *(const bf16x8*)(p + frag_off(row, c0));
}

__global__ __launch_bounds__(256)
void attn_fallback(const float* __restrict__ qkv, float* __restrict__ out) {
    const int h     = blockIdx.y;
    const int t0    = blockIdx.x * TQ;
    const int tid   = threadIdx.x;
    const int lane  = tid & 63;
    const int strip = tid >> 6;
    const int ln    = lane & 15;
    const int q4    = lane >> 4;

    __shared__ unsigned short Qs[TQ * D];
    __shared__ unsigned short Ks[64 * D];
    __shared__ unsigned short Vs[D * 64];
    __shared__ unsigned short Pss[TQ * 64];
    __shared__ float l_lds[TQ];

    const float* qb = qkv + (size_t)h * 3 * D * T;
    const float* kb = qb + (size_t)D * T;
    const float* vb = qb + (size_t)(2 * D) * T;
    const int s4 = tid & 15;
    const int c0 = (tid >> 4) * 4;
    {
        float fr[4][4];
        #pragma unroll
        for (int r = 0; r < 4; r++)
            *(f32x4*)fr[r] = *(const f32x4*)(qb + (size_t)(c0 + r) * T + t0 + s4 * 4);
        #pragma unroll
        for (int j = 0; j < 4; j++) {
            int trow = s4 * 4 + j;
            u16x4 wv = { f2bf(fr[0][j]), f2bf(fr[1][j]), f2bf(fr[2][j]), f2bf(fr[3][j]) };
            *(u16x4*)(Qs + frag_off(trow, c0) + (c0 & 7)) = wv;
        }
    }
    __syncthreads();
    const int arow = strip * 16 + ln;
    const int kg   = q4 * 8;
    const bf16x8 aq0 = frag8(Qs, arow, kg);
    const bf16x8 aq1 = frag8(Qs, arow, 32 + kg);
    f32x4 acc_o[4];
    #pragma unroll
    for (int m = 0; m < 4; m++) acc_o[m] = (f32x4){0.f, 0.f, 0.f, 0.f};
    float l_acc[4] = {0.f, 0.f, 0.f, 0.f};
    constexpr float S2 = 0.125f * 1.44269504088896340736f;
    for (int kt = 0; kt < NT; kt++) {
        const int s0 = kt * 64;
        float kr[4][4], vr[4][4];
        #pragma unroll
        for (int r = 0; r < 4; r++)
            *(f32x4*)kr[r] = *(const f32x4*)(kb + (size_t)(c0 + r) * T + s0 + s4 * 4);
        #pragma unroll
        for (int r = 0; r < 4; r++)
            *(f32x4*)vr[r] = *(const f32x4*)(vb + (size_t)(c0 + r) * T + s0 + s4 * 4);
        __syncthreads();
        #pragma unroll
        for (int j = 0; j < 4; j++) {
            int srow = s4 * 4 + j;
            u16x4 wk = { f2bf(kr[0][j]), f2bf(kr[1][j]), f2bf(kr[2][j]), f2bf(kr[3][j]) };
            *(u16x4*)(Ks + frag_off(srow, c0) + (c0 & 7)) = wk;
        }
        #pragma unroll
        for (int r = 0; r < 4; r++) {
            int row = c0 + r, cc = s4 * 4;
            u16x4 wv = { f2bf(vr[r][0]), f2bf(vr[r][1]), f2bf(vr[r][2]), f2bf(vr[r][3]) };
            *(u16x4*)(Vs + frag_off(row, cc) + (cc & 7)) = wv;
        }
        __syncthreads();
        f32x4 accs[4];
        #pragma unroll
        for (int ns = 0; ns < 4; ns++) {
            bf16x8 b0 = frag8(Ks, ns * 16 + ln, kg);
            bf16x8 b1 = frag8(Ks, ns * 16 + ln, 32 + kg);
            f32x4 z = {0.f, 0.f, 0.f, 0.f};
            z = __builtin_amdgcn_mfma_f32_16x16x32_bf16(aq0, b0, z, 0, 0, 0);
            z = __builtin_amdgcn_mfma_f32_16x16x32_bf16(aq1, b1, z, 0, 0, 0);
            accs[ns] = z;
        }
        #pragma unroll
        for (int ns = 0; ns < 4; ns++) {
            int scol = ns * 16 + ln;
            #pragma unroll
            for (int r = 0; r < 4; r++) {
                float p = __builtin_amdgcn_exp2f(accs[ns][r] * S2);
                l_acc[r] += p;
                int trow = strip * 16 + q4 * 4 + r;
                int g = ((scol >> 3) ^ ((trow >> 1) & 7));
                Pss[trow * 64 + g * 8 + (scol & 7)] = f2bf(p);
            }
        }
        bf16x8 bp0 = frag8(Pss, arow, kg);
        bf16x8 bp1 = frag8(Pss, arow, 32 + kg);
        #pragma unroll
        for (int ms = 0; ms < 4; ms++) {
            bf16x8 av0 = frag8(Vs, ms * 16 + ln, kg);
            bf16x8 av1 = frag8(Vs, ms * 16 + ln, 32 + kg);
            acc_o[ms] = __builtin_amdgcn_mfma_f32_16x16x32_bf16(av0, bp0, acc_o[ms], 0, 0, 0);
            acc_o[ms] = __builtin_amdgcn_mfma_f32_16x16x32_bf16(av1, bp1, acc_o[ms], 0, 0, 0);
        }
    }
    #pragma unroll
    for (int r = 0; r < 4; r++) {
        float s = l_acc[r];
        s += __shfl_xor(s, 1, 64);
        s += __shfl_xor(s, 2, 64);
        s += __shfl_xor(s, 4, 64);
        s += __shfl_xor(s, 8, 64);
        if (ln == 0) l_lds[strip * 16 + q4 * 4 + r] = s;
    }
    const float linv = 1.0f / l_lds[strip * 16 + ln];
    const int tg = t0 + strip * 16 + ln;
    float* ob = out + (size_t)h * D * T;
    #pragma unroll
    for (int ms = 0; ms < 4; ms++)
        #pragma unroll
        for (int r = 0; r < 4; r++) {
            int c = ms * 16 + q4 * 4 + r;
            ob[(size_t)c * T + tg] = acc_o[ms][r] * linv;
        }
}

} // namespace

extern "C" void kernel_launch(void* const* d_in, const int* in_sizes, int n_in,
                              void* d_out, int out_size, void* d_ws, size_t ws_size,
                              hipStream_t stream) {
    const float* qkv = (const float*)d_in[0];
    float* out = (float*)d_out;
    if (ws_size >= WS_NEED) {
        prepass<<<dim3(32, 64, 2), 256, 0, stream>>>(qkv, (unsigned short*)d_ws);
        attn_main<<<dim3(64, 32), 256, 0, stream>>>((const unsigned short*)d_ws, qkv, out);
    } else {
        attn_fallback<<<dim3(32, 64), 256, 0, stream>>>(qkv, out);
    }
}

// Round 3
// 257.769 us; speedup vs baseline: 1.4074x; 1.4074x over previous
//
#include <hip/hip_runtime.h>

namespace {

constexpr int D  = 64;    // channels per head
constexpr int T  = 2048;  // sequence length
constexpr int TQ = 64;    // queries per block
constexpr int NT = T / 64;
constexpr float SCL = 0.125f * 1.44269504088896340736f;  // scale^2 * log2(e)

// workspace layout (units: unsigned short): KV tiles only: (h*32+kt)*8192
//   K: first 4096 shorts, [s][c] rows of 64, granule-swizzled
//   V: next 4096 shorts, QUARTER-BLOCKED: quarter wq (2 KB) = rows c of 16 s,
//      granules of 4 shorts swizzled g^((c>>2)&3)
// Q is NOT staged: attn_main transposes it in-LDS from fp32 directly.
constexpr size_t WS_NEED = (size_t)64 * 32 * 8192 * 2;   // 33554432 B

typedef __bf16 bf16x8 __attribute__((ext_vector_type(8)));
typedef float  f32x4  __attribute__((ext_vector_type(4)));
typedef unsigned short u16x4 __attribute__((ext_vector_type(4)));
typedef unsigned short u16x8 __attribute__((ext_vector_type(8)));
typedef unsigned int   u32x2 __attribute__((ext_vector_type(2)));
typedef short          s16x4 __attribute__((ext_vector_type(4)));

__device__ inline unsigned short f2bf(float f) {   // RNE fp32->bf16, finite inputs
    unsigned int u = __builtin_bit_cast(unsigned int, f);
    u += 0x7FFFu + ((u >> 16) & 1u);
    return (unsigned short)(u >> 16);
}

__device__ inline unsigned int pkbf(float a, float b) {
#if __has_builtin(__builtin_amdgcn_cvt_pk_bf16_f32)
    auto r = __builtin_amdgcn_cvt_pk_bf16_f32(a, b);
    static_assert(sizeof(r) == 4, "cvt_pk_bf16 size");
    return __builtin_bit_cast(unsigned int, r);
#else
    return (unsigned int)f2bf(a) | ((unsigned int)f2bf(b) << 16);
#endif
}

// 64-short rows, 16B granules XOR-swizzled by ((row>>1)&7) (K/Q images).
__device__ inline int frag_off(int row, int c0) {
    int g = (c0 >> 3) ^ ((row >> 1) & 7);
    return row * 64 + g * 8;
}

__device__ inline void async_cp16(const void* g, void* l) {
    __builtin_amdgcn_global_load_lds(
        (const __attribute__((address_space(1))) unsigned int*)g,
        (__attribute__((address_space(3))) unsigned int*)l, 16, 0, 0);
}

// ---------------- pre-pass: K,V fp32 -> bf16 swizzled tiles ------------------
__global__ __launch_bounds__(256)
void prepass(const float* __restrict__ qkv, unsigned short* __restrict__ ws) {
    const int tile = blockIdx.x, h = blockIdx.y, zz = blockIdx.z;  // zz: 0=K, 1=V
    const int tid = threadIdx.x;
    const float* src = qkv + (size_t)h * 3 * D * T + (size_t)(zz + 1) * D * T + tile * 64;
    __shared__ unsigned short L[4096];

    if (zz == 1) {  // V: quarter-blocked [wq][c][16s], granule(4sh) swizzle g^((c>>2)&3)
        unsigned short* dst = ws + (size_t)(h * 32 + tile) * 8192 + 4096;
        const int c = tid >> 2, g = tid & 3;
        const int sg = g ^ ((c >> 2) & 3);           // source granule (s-local/4)
        #pragma unroll
        for (int wq = 0; wq < 4; wq++) {
            f32x4 a = *(const f32x4*)(src + (size_t)c * T + wq * 16 + sg * 4);
            u16x4 wv = { f2bf(a[0]), f2bf(a[1]), f2bf(a[2]), f2bf(a[3]) };
            *(u16x4*)(dst + wq * 1024 + tid * 4) = wv;   // coalesced 8B stores
        }
    } else {       // K: transpose [c][t] -> swizzled [t][c] via LDS
        const int c0 = (tid >> 4) * 4, s4 = tid & 15;
        float fr[4][4];
        #pragma unroll
        for (int r = 0; r < 4; r++)
            *(f32x4*)fr[r] = *(const f32x4*)(src + (size_t)(c0 + r) * T + s4 * 4);
        #pragma unroll
        for (int j = 0; j < 4; j++) {
            int trow = s4 * 4 + j;
            u16x4 wv = { f2bf(fr[0][j]), f2bf(fr[1][j]),
                         f2bf(fr[2][j]), f2bf(fr[3][j]) };
            *(u16x4*)(L + frag_off(trow, c0) + (c0 & 7)) = wv;
        }
        __syncthreads();
        unsigned short* dst = ws + (size_t)(h * 32 + tile) * 8192;
        #pragma unroll
        for (int i = 0; i < 2; i++)
            *(u16x8*)(dst + tid * 16 + i * 8) = *(const u16x8*)(L + tid * 16 + i * 8);
    }
}

// ---------------- main: barrier-free-loop flash attention --------------------
// Block = 4 waves; wave w owns s-quarter [16w,16w+16), all 64 t.
// EXACT R0 loop structure (proven 106 us): double-buffered wave-private
// staging (2 x 4KB), stage distance 1, vmcnt(4), in-body ds_reads, zero
// __syncthreads in the K-loop. Only the prologue differs from R0: Q is
// loaded fp32 from qkv, scaled, transposed in-LDS into the (then-dead)
// buf1 slots, and read into registers before the loop begins.

#define STAGE(J, B)                                                          \
  { const char* g = kvb + (size_t)(J) * 16384;                               \
    char* lk = wbase + (B) * 4096;                                           \
    async_cp16(g,               lk);                                         \
    async_cp16(g + 1024,        lk + 1024);                                  \
    async_cp16(g + 8192,        lk + 2048);                                  \
    async_cp16(g + 8192 + 1024, lk + 3072); }

#define BODY(KT, B, DO_STAGE, WAITIMM)                                       \
  {                                                                          \
    __builtin_amdgcn_s_waitcnt(0xC07F);  /* lgkmcnt(0): WAR guard */         \
    if (DO_STAGE) STAGE((KT) + 1, (B) ^ 1)                                   \
    __builtin_amdgcn_s_waitcnt(WAITIMM); /* vmcnt(N): tile KT landed */      \
    bf16x8 aK0 = *(const bf16x8*)aKp[B][0];                                  \
    bf16x8 aK1 = *(const bf16x8*)aKp[B][1];                                  \
    s16x4 aV0 = *(const s16x4*)aVp[B][0];                                    \
    s16x4 aV1 = *(const s16x4*)aVp[B][1];                                    \
    s16x4 aV2 = *(const s16x4*)aVp[B][2];                                    \
    s16x4 aV3 = *(const s16x4*)aVp[B][3];                                    \
    f32x4 acc_s[4];                                                          \
    _Pragma("unroll")                                                        \
    for (int ti = 0; ti < 4; ti++)                                           \
      acc_s[ti] = __builtin_amdgcn_mfma_f32_16x16x32_bf16(                   \
          aK0, bQ[ti][0], ZF, 0, 0, 0);                                      \
    _Pragma("unroll")                                                        \
    for (int ti = 0; ti < 4; ti++)                                           \
      acc_s[ti] = __builtin_amdgcn_mfma_f32_16x16x32_bf16(                   \
          aK1, bQ[ti][1], acc_s[ti], 0, 0, 0);                               \
    s16x4 bP[4];                                                             \
    _Pragma("unroll")                                                        \
    for (int ti = 0; ti < 4; ti++) {                                         \
      float p0 = __builtin_amdgcn_exp2f(acc_s[ti][0]);                       \
      float p1 = __builtin_amdgcn_exp2f(acc_s[ti][1]);                       \
      float p2 = __builtin_amdgcn_exp2f(acc_s[ti][2]);                       \
      float p3 = __builtin_amdgcn_exp2f(acc_s[ti][3]);                       \
      l_acc[ti] += (p0 + p1) + (p2 + p3);                                    \
      u32x2 pk = { pkbf(p0, p1), pkbf(p2, p3) };                             \
      bP[ti] = __builtin_bit_cast(s16x4, pk);                                \
    }                                                                        \
    _Pragma("unroll")                                                        \
    for (int ti = 0; ti < 4; ti++) {                                         \
      acc_o[0][ti] = __builtin_amdgcn_mfma_f32_16x16x16bf16_1k(              \
          aV0, bP[ti], acc_o[0][ti], 0, 0, 0);                               \
      acc_o[1][ti] = __builtin_amdgcn_mfma_f32_16x16x16bf16_1k(              \
          aV1, bP[ti], acc_o[1][ti], 0, 0, 0);                               \
      acc_o[2][ti] = __builtin_amdgcn_mfma_f32_16x16x16bf16_1k(              \
          aV2, bP[ti], acc_o[2][ti], 0, 0, 0);                               \
      acc_o[3][ti] = __builtin_amdgcn_mfma_f32_16x16x16bf16_1k(              \
          aV3, bP[ti], acc_o[3][ti], 0, 0, 0);                               \
    }                                                                        \
  }

__global__ __launch_bounds__(256, 3)
void attn_main(const unsigned short* __restrict__ ws,
               const float* __restrict__ qkv, float* __restrict__ out) {
    const int h  = blockIdx.x;      // head pinned to XCD h%8 for L2 locality
    const int qt = blockIdx.y;
    const int t0 = qt * TQ;
    const int tid  = threadIdx.x;
    const int lane = tid & 63;
    const int w    = tid >> 6;      // wave id = s-quarter
    const int ln   = lane & 15, q4 = lane >> 4;

    __shared__ char  sbuf[32768];   // 4 waves x (dbuf x (2K K + 2K V)); merge scratch
    __shared__ float lbuf[256];     // l partials [wave][t]
    char* wbase = sbuf + w * 8192;
    unsigned short* S16 = (unsigned short*)sbuf;

    // ---- prologue: fp32 Q loads + tile-0 staging (overlapped) ----
    const float* qsrc = qkv + (size_t)h * 3 * D * T + t0;
    const int c0 = (tid >> 4) * 4, s4 = tid & 15;
    float fr[4][4];
    #pragma unroll
    for (int r = 0; r < 4; r++)
        *(f32x4*)fr[r] = *(const f32x4*)(qsrc + (size_t)(c0 + r) * T + s4 * 4);

    const char* kvb = (const char*)ws + (size_t)(h * 32) * 16384
                      + (size_t)w * 2048 + lane * 16;
    STAGE(0, 0)                      // tile 0 -> buf 0 (async, overlaps Q work)

    // Q -> bf16 swizzled image in the 4 buf1 slots (wave ti's wbase+4096),
    // chunk ti (2048 shorts) = rows t in [16*ti, 16*ti+16). Same row swizzle as K.
    #pragma unroll
    for (int j = 0; j < 4; j++) {
        int trow = s4 * 4 + j;
        int g = (c0 >> 3) ^ ((trow >> 1) & 7);
        u16x4 wv = { f2bf(fr[0][j] * SCL), f2bf(fr[1][j] * SCL),
                     f2bf(fr[2][j] * SCL), f2bf(fr[3][j] * SCL) };
        *(u16x4*)(S16 + (trow >> 4) * 4096 + 2048 + (trow & 15) * 64 + g * 8 + (c0 & 7)) = wv;
    }
    __syncthreads();                 // Q image visible (also drains tile-0 cps)
    bf16x8 bQ[4][2];
    #pragma unroll
    for (int ti = 0; ti < 4; ti++)
        #pragma unroll
        for (int kc = 0; kc < 2; kc++) {
            int cc = kc * 32 + q4 * 8;
            int g = (cc >> 3) ^ ((ln >> 1) & 7);   // (row>>1)&7 == (ln>>1)&7 for row=16*ti+ln
            bQ[ti][kc] = *(const bf16x8*)(S16 + ti * 4096 + 2048 + ln * 64 + g * 8);
        }
    __syncthreads();                 // all bQ reads done; buf1 slots reusable

    // wave-private LDS fragment pointers (both buffers) — exact R0 form
    const unsigned short* aKp[2][2];
    const unsigned short* aVp[2][4];
    const int vsw = (q4 ^ ((ln >> 2) & 3)) * 4;   // V granule swizzle (ci-invariant)
    #pragma unroll
    for (int b = 0; b < 2; b++) {
        const unsigned short* base = (const unsigned short*)(wbase + b * 4096);
        #pragma unroll
        for (int kc = 0; kc < 2; kc++)
            aKp[b][kc] = base + frag_off(ln, kc * 32 + q4 * 8);
        #pragma unroll
        for (int ci = 0; ci < 4; ci++)
            aVp[b][ci] = base + 1024 + (16 * ci + ln) * 16 + vsw;
    }
    const f32x4 ZF = {0.f, 0.f, 0.f, 0.f};

    f32x4 acc_o[4][4];   // [ci][ti], partial over this wave's s-quarter
    #pragma unroll
    for (int ci = 0; ci < 4; ci++)
        #pragma unroll
        for (int ti = 0; ti < 4; ti++) acc_o[ci][ti] = ZF;
    float l_acc[4] = {0.f, 0.f, 0.f, 0.f};

    #pragma unroll 1
    for (int m = 0; m < 15; m++) {   // kt = 0..29
        BODY(2 * m,     0, 1, 0x0F74)
        BODY(2 * m + 1, 1, 1, 0x0F74)
    }
    BODY(30, 0, 1, 0x0F74)           // stages tile 31
    BODY(31, 1, 0, 0x0F70)           // vmcnt(0): last tile fully landed

    // ---- epilogue: XOR-butterfly merge of 4 s-quarter partials (exact R0) ----
    __syncthreads();                 // first barrier since prologue
    #pragma unroll
    for (int ti = 0; ti < 4; ti++) { // l: reduce over q4, publish per-wave
        float s = l_acc[ti];
        s += __shfl_xor(s, 16, 64);
        s += __shfl_xor(s, 32, 64);
        if (q4 == 0) lbuf[w * 64 + ti * 16 + ln] = s;
    }
    float* slots = (float*)sbuf;     // region[w] = 8 KB (2048 floats)
    // round 1: exchange with w^1 on bit0
    #pragma unroll
    for (int q = 0; q < 4; q++)
        if ((q ^ w) & 1) {
            float* dst = slots + w * 2048 + (q >> 1) * 1024;
            #pragma unroll
            for (int ti = 0; ti < 4; ti++)
                *(f32x4*)(dst + ti * 256 + lane * 4) = acc_o[q][ti];
        }
    __syncthreads();
    #pragma unroll
    for (int q = 0; q < 4; q++)
        if (!((q ^ w) & 1)) {
            const float* srcp = slots + (w ^ 1) * 2048 + (q >> 1) * 1024;
            #pragma unroll
            for (int ti = 0; ti < 4; ti++)
                acc_o[q][ti] += *(const f32x4*)(srcp + ti * 256 + lane * 4);
        }
    __syncthreads();
    // round 2: exchange with w^2 on bit1
    #pragma unroll
    for (int q = 0; q < 4; q++)
        if (((q ^ w) & 3) == 2) {
            float* dst = slots + w * 2048;
            #pragma unroll
            for (int ti = 0; ti < 4; ti++)
                *(f32x4*)(dst + ti * 256 + lane * 4) = acc_o[q][ti];
        }
    __syncthreads();
    #pragma unroll
    for (int q = 0; q < 4; q++)
        if (q == w) {
            const float* srcp = slots + (w ^ 2) * 2048;
            float linv[4];
            #pragma unroll
            for (int ti = 0; ti < 4; ti++) {
                int tt = ti * 16 + ln;
                linv[ti] = 1.0f / (lbuf[tt] + lbuf[64 + tt] +
                                   lbuf[128 + tt] + lbuf[192 + tt]);
                acc_o[q][ti] += *(const f32x4*)(srcp + ti * 256 + lane * 4);
            }
            float* ob = out + (size_t)h * D * T + t0;
            #pragma unroll
            for (int ti = 0; ti < 4; ti++)
                #pragma unroll
                for (int rr = 0; rr < 4; rr++) {
                    int c = 16 * w + q4 * 4 + rr;
                    ob[(size_t)c * T + ti * 16 + ln] = acc_o[q][ti][rr] * linv[ti];
                }
        }
}

// ---------------- fallback (R2 kernel, proven): used if ws too small ----------
__device__ inline bf16x8 frag8(const unsigned short* p, int row, int c0) {
    return *(const bf16x8*)(p + frag_off(row, c0));
}

__global__ __launch_bounds__(256)
void attn_fallback(const float* __restrict__ qkv, float* __restrict__ out) {
    const int h     = blockIdx.y;
    const int t0    = blockIdx.x * TQ;
    const int tid   = threadIdx.x;
    const int lane  = tid & 63;
    const int strip = tid >> 6;
    const int ln    = lane & 15;
    const int q4    = lane >> 4;

    __shared__ unsigned short Qs[TQ * D];
    __shared__ unsigned short Ks[64 * D];
    __shared__ unsigned short Vs[D * 64];
    __shared__ unsigned short Pss[TQ * 64];
    __shared__ float l_lds[TQ];

    const float* qb = qkv + (size_t)h * 3 * D * T;
    const float* kb = qb + (size_t)D * T;
    const float* vb = qb + (size_t)(2 * D) * T;
    const int s4 = tid & 15;
    const int c0 = (tid >> 4) * 4;
    {
        float fr[4][4];
        #pragma unroll
        for (int r = 0; r < 4; r++)
            *(f32x4*)fr[r] = *(const f32x4*)(qb + (size_t)(c0 + r) * T + t0 + s4 * 4);
        #pragma unroll
        for (int j = 0; j < 4; j++) {
            int trow = s4 * 4 + j;
            u16x4 wv = { f2bf(fr[0][j]), f2bf(fr[1][j]), f2bf(fr[2][j]), f2bf(fr[3][j]) };
            *(u16x4*)(Qs + frag_off(trow, c0) + (c0 & 7)) = wv;
        }
    }
    __syncthreads();
    const int arow = strip * 16 + ln;
    const int kg   = q4 * 8;
    const bf16x8 aq0 = frag8(Qs, arow, kg);
    const bf16x8 aq1 = frag8(Qs, arow, 32 + kg);
    f32x4 acc_o[4];
    #pragma unroll
    for (int m = 0; m < 4; m++) acc_o[m] = (f32x4){0.f, 0.f, 0.f, 0.f};
    float l_acc[4] = {0.f, 0.f, 0.f, 0.f};
    constexpr float S2 = 0.125f * 1.44269504088896340736f;
    for (int kt = 0; kt < NT; kt++) {
        const int s0 = kt * 64;
        float kr[4][4], vr[4][4];
        #pragma unroll
        for (int r = 0; r < 4; r++)
            *(f32x4*)kr[r] = *(const f32x4*)(kb + (size_t)(c0 + r) * T + s0 + s4 * 4);
        #pragma unroll
        for (int r = 0; r < 4; r++)
            *(f32x4*)vr[r] = *(const f32x4*)(vb + (size_t)(c0 + r) * T + s0 + s4 * 4);
        __syncthreads();
        #pragma unroll
        for (int j = 0; j < 4; j++) {
            int srow = s4 * 4 + j;
            u16x4 wk = { f2bf(kr[0][j]), f2bf(kr[1][j]), f2bf(kr[2][j]), f2bf(kr[3][j]) };
            *(u16x4*)(Ks + frag_off(srow, c0) + (c0 & 7)) = wk;
        }
        #pragma unroll
        for (int r = 0; r < 4; r++) {
            int row = c0 + r, cc = s4 * 4;
            u16x4 wv = { f2bf(vr[r][0]), f2bf(vr[r][1]), f2bf(vr[r][2]), f2bf(vr[r][3]) };
            *(u16x4*)(Vs + frag_off(row, cc) + (cc & 7)) = wv;
        }
        __syncthreads();
        f32x4 accs[4];
        #pragma unroll
        for (int ns = 0; ns < 4; ns++) {
            bf16x8 b0 = frag8(Ks, ns * 16 + ln, kg);
            bf16x8 b1 = frag8(Ks, ns * 16 + ln, 32 + kg);
            f32x4 z = {0.f, 0.f, 0.f, 0.f};
            z = __builtin_amdgcn_mfma_f32_16x16x32_bf16(aq0, b0, z, 0, 0, 0);
            z = __builtin_amdgcn_mfma_f32_16x16x32_bf16(aq1, b1, z, 0, 0, 0);
            accs[ns] = z;
        }
        #pragma unroll
        for (int ns = 0; ns < 4; ns++) {
            int scol = ns * 16 + ln;
            #pragma unroll
            for (int r = 0; r < 4; r++) {
                float p = __builtin_amdgcn_exp2f(accs[ns][r] * S2);
                l_acc[r] += p;
                int trow = strip * 16 + q4 * 4 + r;
                int g = ((scol >> 3) ^ ((trow >> 1) & 7));
                Pss[trow * 64 + g * 8 + (scol & 7)] = f2bf(p);
            }
        }
        bf16x8 bp0 = frag8(Pss, arow, kg);
        bf16x8 bp1 = frag8(Pss, arow, 32 + kg);
        #pragma unroll
        for (int ms = 0; ms < 4; ms++) {
            bf16x8 av0 = frag8(Vs, ms * 16 + ln, kg);
            bf16x8 av1 = frag8(Vs, ms * 16 + ln, 32 + kg);
            acc_o[ms] = __builtin_amdgcn_mfma_f32_16x16x32_bf16(av0, bp0, acc_o[ms], 0, 0, 0);
            acc_o[ms] = __builtin_amdgcn_mfma_f32_16x16x32_bf16(av1, bp1, acc_o[ms], 0, 0, 0);
        }
    }
    #pragma unroll
    for (int r = 0; r < 4; r++) {
        float s = l_acc[r];
        s += __shfl_xor(s, 1, 64);
        s += __shfl_xor(s, 2, 64);
        s += __shfl_xor(s, 4, 64);
        s += __shfl_xor(s, 8, 64);
        if (ln == 0) l_lds[strip * 16 + q4 * 4 + r] = s;
    }
    const float linv = 1.0f / l_lds[strip * 16 + ln];
    const int tg = t0 + strip * 16 + ln;
    float* ob = out + (size_t)h * D * T;
    #pragma unroll
    for (int ms = 0; ms < 4; ms++)
        #pragma unroll
        for (int r = 0; r < 4; r++) {
            int c = ms * 16 + q4 * 4 + r;
            ob[(size_t)c * T + tg] = acc_o[ms][r] * linv;
        }
}

} // namespace

extern "C" void kernel_launch(void* const* d_in, const int* in_sizes, int n_in,
                              void* d_out, int out_size, void* d_ws, size_t ws_size,
                              hipStream_t stream) {
    const float* qkv = (const float*)d_in[0];
    float* out = (float*)d_out;
    if (ws_size >= WS_NEED) {
        prepass<<<dim3(32, 64, 2), 256, 0, stream>>>(qkv, (unsigned short*)d_ws);
        attn_main<<<dim3(64, 32), 256, 0, stream>>>((const unsigned short*)d_ws, qkv, out);
    } else {
        attn_fallback<<<dim3(32, 64), 256, 0, stream>>>(qkv, out);
    }
}

// Round 4
// 254.098 us; speedup vs baseline: 1.4277x; 1.0144x over previous
//
#include <hip/hip_runtime.h>

namespace {

constexpr int D  = 64;    // channels per head
constexpr int T  = 2048;  // sequence length
constexpr int TQ = 64;    // queries per block
constexpr int NT = T / 64;
constexpr float SCL = 0.125f * 1.44269504088896340736f;  // scale^2 * log2(e)

// workspace layout (units: unsigned short):
//  [0, 64*32*8192)             KV tiles: (h*32+kt)*8192
//     K: first 4096 shorts, [s][c] rows of 64, granule-swizzled (16-row quarter = contiguous 2 KB)
//     V: next 4096 shorts, QUARTER-BLOCKED: quarter q (2 KB) = rows c of 16 s, granules of 4 shorts swizzled g^((c>>2)&3)
//  [QP_OFF, ...)               Q tiles: (h*32+qt)*4096 swizzled [t][c], PRE-SCALED by SCL
constexpr size_t QP_OFF  = (size_t)64 * 32 * 8192;
constexpr size_t WS_NEED = ((size_t)64 * 32 * 8192 + (size_t)64 * 32 * 4096) * 2;  // 50331648 B

typedef __bf16 bf16x8 __attribute__((ext_vector_type(8)));
typedef float  f32x4  __attribute__((ext_vector_type(4)));
typedef unsigned short u16x4 __attribute__((ext_vector_type(4)));
typedef unsigned short u16x8 __attribute__((ext_vector_type(8)));
typedef unsigned int   u32x2 __attribute__((ext_vector_type(2)));
typedef short          s16x4 __attribute__((ext_vector_type(4)));

__device__ inline unsigned short f2bf(float f) {   // RNE fp32->bf16, finite inputs
    unsigned int u = __builtin_bit_cast(unsigned int, f);
    u += 0x7FFFu + ((u >> 16) & 1u);
    return (unsigned short)(u >> 16);
}

__device__ inline unsigned int pkbf(float a, float b) {
#if __has_builtin(__builtin_amdgcn_cvt_pk_bf16_f32)
    auto r = __builtin_amdgcn_cvt_pk_bf16_f32(a, b);
    static_assert(sizeof(r) == 4, "cvt_pk_bf16 size");
    return __builtin_bit_cast(unsigned int, r);
#else
    return (unsigned int)f2bf(a) | ((unsigned int)f2bf(b) << 16);
#endif
}

// 64-short rows, 16B granules XOR-swizzled by ((row>>1)&7) (K/Q images).
__device__ inline int frag_off(int row, int c0) {
    int g = (c0 >> 3) ^ ((row >> 1) & 7);
    return row * 64 + g * 8;
}

__device__ inline void async_cp16(const void* g, void* l) {
    __builtin_amdgcn_global_load_lds(
        (const __attribute__((address_space(1))) unsigned int*)g,
        (__attribute__((address_space(3))) unsigned int*)l, 16, 0, 0);
}

// ---------------- pre-pass: fp32 -> bf16, swizzled tiles (exact R0) ----------
__global__ __launch_bounds__(256)
void prepass(const float* __restrict__ qkv, unsigned short* __restrict__ ws) {
    const int tile = blockIdx.x, h = blockIdx.y, z = blockIdx.z;
    const int tid = threadIdx.x;
    const float* src = qkv + (size_t)h * 3 * D * T + (size_t)z * D * T + tile * 64;
    __shared__ unsigned short L[4096];

    if (z == 2) {  // V: quarter-blocked [wq][c][16s], granule(4sh) swizzle g^((c>>2)&3)
        unsigned short* dst = ws + (size_t)(h * 32 + tile) * 8192 + 4096;
        const int c = tid >> 2, g = tid & 3;
        const int sg = g ^ ((c >> 2) & 3);           // source granule (s-local/4)
        #pragma unroll
        for (int wq = 0; wq < 4; wq++) {
            f32x4 a = *(const f32x4*)(src + (size_t)c * T + wq * 16 + sg * 4);
            u16x4 wv = { f2bf(a[0]), f2bf(a[1]), f2bf(a[2]), f2bf(a[3]) };
            *(u16x4*)(dst + wq * 1024 + tid * 4) = wv;   // coalesced 8B stores
        }
    } else {       // Q/K: transpose [c][t] -> swizzled [t][c] via LDS
        const float m = (z == 0) ? SCL : 1.0f;   // fold softmax scale into Q
        const int c0 = (tid >> 4) * 4, s4 = tid & 15;
        float fr[4][4];
        #pragma unroll
        for (int r = 0; r < 4; r++)
            *(f32x4*)fr[r] = *(const f32x4*)(src + (size_t)(c0 + r) * T + s4 * 4);
        #pragma unroll
        for (int j = 0; j < 4; j++) {
            int trow = s4 * 4 + j;
            u16x4 wv = { f2bf(fr[0][j] * m), f2bf(fr[1][j] * m),
                         f2bf(fr[2][j] * m), f2bf(fr[3][j] * m) };
            *(u16x4*)(L + frag_off(trow, c0) + (c0 & 7)) = wv;
        }
        __syncthreads();
        unsigned short* dst = (z == 0)
            ? ws + QP_OFF + (size_t)(h * 32 + tile) * 4096
            : ws + (size_t)(h * 32 + tile) * 8192;
        #pragma unroll
        for (int i = 0; i < 2; i++)
            *(u16x8*)(dst + tid * 16 + i * 8) = *(const u16x8*)(L + tid * 16 + i * 8);
    }
}

// ---------------- main: t-split flash attention, shared staging --------------
// Block = 4 waves; wave w owns Q-rows t in [16w,16w+16), FULL s range.
// Per wave: acc_o = 16t x 64c / 64 lanes = 16 regs (vs 64 in the s-split
// version); bQ = 2 frags; l = 1 scalar; NO cross-wave merge epilogue.
// KV staging is BLOCK-SHARED (16 KB/tile, double-buffered = 32 KB LDS):
//   body KT: vmcnt(4) [own tile-KT cps landed] -> s_barrier [all waves'] ->
//   per-quarter {ds_read K,V frags; QK mfma; exp2; pack; PV mfma} ->
//   lgkmcnt(0) -> s_barrier [reads done] -> STAGE(KT+2 -> buf KT&1).
// Raw s_barrier (NOT __syncthreads: that drains vmcnt and kills the
// pipeline). Stage->wait distance = 2 bodies. Target: 4-5 blocks/CU
// (was 3, reg-capped at ~148 unified).

#define STAGE(J, B)                                                          \
  { const char* g = kvb + (size_t)(J) * 16384;                               \
    char* lk = lbase + (B) * 16384;                                          \
    async_cp16(g,         lk);                                               \
    async_cp16(g + 4096,  lk + 4096);                                        \
    async_cp16(g + 8192,  lk + 8192);                                        \
    async_cp16(g + 12288, lk + 12288); }

#define BODY(KT, B, DO_STAGE, WAITIMM)                                       \
  {                                                                          \
    __builtin_amdgcn_s_waitcnt(WAITIMM);  /* own tile-KT cps landed */       \
    __builtin_amdgcn_s_barrier();         /* ALL waves' tile-KT landed */    \
    __builtin_amdgcn_sched_barrier(0);    /* no ds_read hoists above */      \
    _Pragma("unroll")                                                        \
    for (int q = 0; q < 4; q++) {                                            \
      const char* kb = sbuf + (B) * 16384 + q * 2048;                        \
      const char* vb = sbuf + (B) * 16384 + 8192 + q * 2048;                 \
      bf16x8 aK0 = *(const bf16x8*)(kb + aK0o);                              \
      bf16x8 aK1 = *(const bf16x8*)(kb + aK1o);                              \
      s16x4 aV0 = *(const s16x4*)(vb + aVo);                                 \
      s16x4 aV1 = *(const s16x4*)(vb + aVo + 512);                           \
      s16x4 aV2 = *(const s16x4*)(vb + aVo + 1024);                          \
      s16x4 aV3 = *(const s16x4*)(vb + aVo + 1536);                          \
      f32x4 s = __builtin_amdgcn_mfma_f32_16x16x32_bf16(aK0, bQ0, ZF, 0,0,0);\
      s = __builtin_amdgcn_mfma_f32_16x16x32_bf16(aK1, bQ1, s, 0, 0, 0);     \
      float p0 = __builtin_amdgcn_exp2f(s[0]);                               \
      float p1 = __builtin_amdgcn_exp2f(s[1]);                               \
      float p2 = __builtin_amdgcn_exp2f(s[2]);                               \
      float p3 = __builtin_amdgcn_exp2f(s[3]);                               \
      l_acc += (p0 + p1) + (p2 + p3);                                        \
      u32x2 pk = { pkbf(p0, p1), pkbf(p2, p3) };                             \
      s16x4 bP = __builtin_bit_cast(s16x4, pk);                              \
      acc_o[0] = __builtin_amdgcn_mfma_f32_16x16x16bf16_1k(                  \
          aV0, bP, acc_o[0], 0, 0, 0);                                       \
      acc_o[1] = __builtin_amdgcn_mfma_f32_16x16x16bf16_1k(                  \
          aV1, bP, acc_o[1], 0, 0, 0);                                       \
      acc_o[2] = __builtin_amdgcn_mfma_f32_16x16x16bf16_1k(                  \
          aV2, bP, acc_o[2], 0, 0, 0);                                       \
      acc_o[3] = __builtin_amdgcn_mfma_f32_16x16x16bf16_1k(                  \
          aV3, bP, acc_o[3], 0, 0, 0);                                       \
    }                                                                        \
    if (DO_STAGE) {                                                          \
      __builtin_amdgcn_s_waitcnt(0xC07F);  /* lgkmcnt(0): reads done */      \
      __builtin_amdgcn_s_barrier();        /* buf (B) free to overwrite */   \
      STAGE((KT) + 2, B)                                                     \
    }                                                                        \
  }

__global__ __launch_bounds__(256, 4)
void attn_main(const unsigned short* __restrict__ ws, float* __restrict__ out) {
    const int h  = blockIdx.x;      // head pinned to XCD h%8 for L2 locality
    const int qt = blockIdx.y;
    const int t0 = qt * TQ;
    const int tid  = threadIdx.x;
    const int lane = tid & 63;
    const int w    = tid >> 6;      // wave id = t-strip
    const int ln   = lane & 15, q4 = lane >> 4;

    __shared__ char sbuf[32768];    // 2 x 16KB shared KV staging (dbuf)
    char* lbase = sbuf + w * 1024;  // this wave's staging slice (wave-uniform)

    // per-lane fragment byte offsets (quarter-local; q*2048 / ci*512 are imms)
    const int aK0o = 2 * frag_off(ln, q4 * 8);
    const int aK1o = 2 * frag_off(ln, 32 + q4 * 8);
    const int aVo  = 32 * ln + 2 * ((q4 ^ ((ln >> 2) & 3)) * 4);

    // Q fragments: rows 16w+ln only (t-split) — 2 global 16B loads
    const unsigned short* qtile = ws + QP_OFF + (size_t)(h * 32 + qt) * 4096;
    bf16x8 bQ0 = *(const bf16x8*)(qtile + frag_off(16 * w + ln, q4 * 8));
    bf16x8 bQ1 = *(const bf16x8*)(qtile + frag_off(16 * w + ln, 32 + q4 * 8));

    const char* kvb = (const char*)ws + (size_t)(h * 32) * 16384
                      + w * 1024 + lane * 16;
    STAGE(0, 0)                      // tiles 0,1 in flight (8 cps + 2 bQ)
    STAGE(1, 1)

    const f32x4 ZF = {0.f, 0.f, 0.f, 0.f};
    f32x4 acc_o[4] = {ZF, ZF, ZF, ZF};   // [ci]: O rows c=16ci+q4*4+rr, col t=ln
    float l_acc = 0.f;

    #pragma unroll 1
    for (int m = 0; m < 15; m++) {   // kt = 0..29
        BODY(2 * m,     0, 1, 0x0F74)   // vmcnt(4)
        BODY(2 * m + 1, 1, 1, 0x0F74)
    }
    BODY(30, 0, 0, 0x0F74)           // no stage; tile 31 still in flight
    BODY(31, 1, 0, 0x0F70)           // vmcnt(0)

    // ---- epilogue: l over q4 groups, direct store (no LDS, no merge) ----
    float sl = l_acc;
    sl += __shfl_xor(sl, 16, 64);
    sl += __shfl_xor(sl, 32, 64);
    const float linv = 1.0f / sl;
    float* ob = out + (size_t)h * D * T + t0 + 16 * w + ln;
    #pragma unroll
    for (int ci = 0; ci < 4; ci++)
        #pragma unroll
        for (int rr = 0; rr < 4; rr++)
            ob[(size_t)(16 * ci + q4 * 4 + rr) * T] = acc_o[ci][rr] * linv;
}

// ---------------- fallback (proven): used if ws too small --------------------
__device__ inline bf16x8 frag8(const unsigned short* p, int row, int c0) {
    return *(const bf16x8*)(p + frag_off(row, c0));
}

__global__ __launch_bounds__(256)
void attn_fallback(const float* __restrict__ qkv, float* __restrict__ out) {
    const int h     = blockIdx.y;
    const int t0    = blockIdx.x * TQ;
    const int tid   = threadIdx.x;
    const int lane  = tid & 63;
    const int strip = tid >> 6;
    const int ln    = lane & 15;
    const int q4    = lane >> 4;

    __shared__ unsigned short Qs[TQ * D];
    __shared__ unsigned short Ks[64 * D];
    __shared__ unsigned short Vs[D * 64];
    __shared__ unsigned short Pss[TQ * 64];
    __shared__ float l_lds[TQ];

    const float* qb = qkv + (size_t)h * 3 * D * T;
    const float* kb = qb + (size_t)D * T;
    const float* vb = qb + (size_t)(2 * D) * T;
    const int s4 = tid & 15;
    const int c0 = (tid >> 4) * 4;
    {
        float fr[4][4];
        #pragma unroll
        for (int r = 0; r < 4; r++)
            *(f32x4*)fr[r] = *(const f32x4*)(qb + (size_t)(c0 + r) * T + t0 + s4 * 4);
        #pragma unroll
        for (int j = 0; j < 4; j++) {
            int trow = s4 * 4 + j;
            u16x4 wv = { f2bf(fr[0][j]), f2bf(fr[1][j]), f2bf(fr[2][j]), f2bf(fr[3][j]) };
            *(u16x4*)(Qs + frag_off(trow, c0) + (c0 & 7)) = wv;
        }
    }
    __syncthreads();
    const int arow = strip * 16 + ln;
    const int kg   = q4 * 8;
    const bf16x8 aq0 = frag8(Qs, arow, kg);
    const bf16x8 aq1 = frag8(Qs, arow, 32 + kg);
    f32x4 acc_o[4];
    #pragma unroll
    for (int m = 0; m < 4; m++) acc_o[m] = (f32x4){0.f, 0.f, 0.f, 0.f};
    float l_acc[4] = {0.f, 0.f, 0.f, 0.f};
    constexpr float S2 = 0.125f * 1.44269504088896340736f;
    for (int kt = 0; kt < NT; kt++) {
        const int s0 = kt * 64;
        float kr[4][4], vr[4][4];
        #pragma unroll
        for (int r = 0; r < 4; r++)
            *(f32x4*)kr[r] = *(const f32x4*)(kb + (size_t)(c0 + r) * T + s0 + s4 * 4);
        #pragma unroll
        for (int r = 0; r < 4; r++)
            *(f32x4*)vr[r] = *(const f32x4*)(vb + (size_t)(c0 + r) * T + s0 + s4 * 4);
        __syncthreads();
        #pragma unroll
        for (int j = 0; j < 4; j++) {
            int srow = s4 * 4 + j;
            u16x4 wk = { f2bf(kr[0][j]), f2bf(kr[1][j]), f2bf(kr[2][j]), f2bf(kr[3][j]) };
            *(u16x4*)(Ks + frag_off(srow, c0) + (c0 & 7)) = wk;
        }
        #pragma unroll
        for (int r = 0; r < 4; r++) {
            int row = c0 + r, cc = s4 * 4;
            u16x4 wv = { f2bf(vr[r][0]), f2bf(vr[r][1]), f2bf(vr[r][2]), f2bf(vr[r][3]) };
            *(u16x4*)(Vs + frag_off(row, cc) + (cc & 7)) = wv;
        }
        __syncthreads();
        f32x4 accs[4];
        #pragma unroll
        for (int ns = 0; ns < 4; ns++) {
            bf16x8 b0 = frag8(Ks, ns * 16 + ln, kg);
            bf16x8 b1 = frag8(Ks, ns * 16 + ln, 32 + kg);
            f32x4 z = {0.f, 0.f, 0.f, 0.f};
            z = __builtin_amdgcn_mfma_f32_16x16x32_bf16(aq0, b0, z, 0, 0, 0);
            z = __builtin_amdgcn_mfma_f32_16x16x32_bf16(aq1, b1, z, 0, 0, 0);
            accs[ns] = z;
        }
        #pragma unroll
        for (int ns = 0; ns < 4; ns++) {
            int scol = ns * 16 + ln;
            #pragma unroll
            for (int r = 0; r < 4; r++) {
                float p = __builtin_amdgcn_exp2f(accs[ns][r] * S2);
                l_acc[r] += p;
                int trow = strip * 16 + q4 * 4 + r;
                int g = ((scol >> 3) ^ ((trow >> 1) & 7));
                Pss[trow * 64 + g * 8 + (scol & 7)] = f2bf(p);
            }
        }
        bf16x8 bp0 = frag8(Pss, arow, kg);
        bf16x8 bp1 = frag8(Pss, arow, 32 + kg);
        #pragma unroll
        for (int ms = 0; ms < 4; ms++) {
            bf16x8 av0 = frag8(Vs, ms * 16 + ln, kg);
            bf16x8 av1 = frag8(Vs, ms * 16 + ln, 32 + kg);
            acc_o[ms] = __builtin_amdgcn_mfma_f32_16x16x32_bf16(av0, bp0, acc_o[ms], 0, 0, 0);
            acc_o[ms] = __builtin_amdgcn_mfma_f32_16x16x32_bf16(av1, bp1, acc_o[ms], 0, 0, 0);
        }
    }
    #pragma unroll
    for (int r = 0; r < 4; r++) {
        float s = l_acc[r];
        s += __shfl_xor(s, 1, 64);
        s += __shfl_xor(s, 2, 64);
        s += __shfl_xor(s, 4, 64);
        s += __shfl_xor(s, 8, 64);
        if (ln == 0) l_lds[strip * 16 + q4 * 4 + r] = s;
    }
    const float linv = 1.0f / l_lds[strip * 16 + ln];
    const int tg = t0 + strip * 16 + ln;
    float* ob = out + (size_t)h * D * T;
    #pragma unroll
    for (int ms = 0; ms < 4; ms++)
        #pragma unroll
        for (int r = 0; r < 4; r++) {
            int c = ms * 16 + q4 * 4 + r;
            ob[(size_t)c * T + tg] = acc_o[ms][r] * linv;
        }
}

} // namespace

extern "C" void kernel_launch(void* const* d_in, const int* in_sizes, int n_in,
                              void* d_out, int out_size, void* d_ws, size_t ws_size,
                              hipStream_t stream) {
    const float* qkv = (const float*)d_in[0];
    float* out = (float*)d_out;
    if (ws_size >= WS_NEED) {
        prepass<<<dim3(32, 64, 3), 256, 0, stream>>>(qkv, (unsigned short*)d_ws);
        attn_main<<<dim3(64, 32), 256, 0, stream>>>((const unsigned short*)d_ws, out);
    } else {
        attn_fallback<<<dim3(32, 64), 256, 0, stream>>>(qkv, out);
    }
}

// Round 5
// 247.151 us; speedup vs baseline: 1.4679x; 1.0281x over previous
//
#include <hip/hip_runtime.h>

namespace {

constexpr int D  = 64;    // channels per head
constexpr int T  = 2048;  // sequence length
constexpr int NT = T / 64;
constexpr float SCL = 0.125f * 1.44269504088896340736f;  // scale^2 * log2(e)

// workspace layout (units: unsigned short):
//  [0, 64*32*8192)             KV tiles: (h*32+kt)*8192
//     K: first 4096 shorts, [s][c] rows of 64, granule-swizzled (16-row quarter = contiguous 2 KB)
//     V: next 4096 shorts, QUARTER-BLOCKED: quarter q (2 KB) = rows c of 16 s, granules of 4 shorts swizzled g^((c>>2)&3)
//  [QP_OFF, ...)               Q tiles: (h*32+qt64)*4096 swizzled [t][c], PRE-SCALED by SCL
constexpr size_t QP_OFF  = (size_t)64 * 32 * 8192;
constexpr size_t WS_NEED = ((size_t)64 * 32 * 8192 + (size_t)64 * 32 * 4096) * 2;  // 50331648 B

typedef __bf16 bf16x8 __attribute__((ext_vector_type(8)));
typedef float  f32x4  __attribute__((ext_vector_type(4)));
typedef unsigned short u16x4 __attribute__((ext_vector_type(4)));
typedef unsigned short u16x8 __attribute__((ext_vector_type(8)));
typedef unsigned int   u32x2 __attribute__((ext_vector_type(2)));
typedef short          s16x4 __attribute__((ext_vector_type(4)));

__device__ inline unsigned short f2bf(float f) {   // RNE fp32->bf16, finite inputs
    unsigned int u = __builtin_bit_cast(unsigned int, f);
    u += 0x7FFFu + ((u >> 16) & 1u);
    return (unsigned short)(u >> 16);
}

__device__ inline unsigned int pkbf(float a, float b) {
#if __has_builtin(__builtin_amdgcn_cvt_pk_bf16_f32)
    auto r = __builtin_amdgcn_cvt_pk_bf16_f32(a, b);
    static_assert(sizeof(r) == 4, "cvt_pk_bf16 size");
    return __builtin_bit_cast(unsigned int, r);
#else
    return (unsigned int)f2bf(a) | ((unsigned int)f2bf(b) << 16);
#endif
}

// 64-short rows, 16B granules XOR-swizzled by ((row>>1)&7) (K/Q images).
__device__ inline int frag_off(int row, int c0) {
    int g = (c0 >> 3) ^ ((row >> 1) & 7);
    return row * 64 + g * 8;
}

__device__ inline void async_cp16(const void* g, void* l) {
    __builtin_amdgcn_global_load_lds(
        (const __attribute__((address_space(1))) unsigned int*)g,
        (__attribute__((address_space(3))) unsigned int*)l, 16, 0, 0);
}

// ---------------- pre-pass: fp32 -> bf16, swizzled tiles (exact R0) ----------
__global__ __launch_bounds__(256)
void prepass(const float* __restrict__ qkv, unsigned short* __restrict__ ws) {
    const int tile = blockIdx.x, h = blockIdx.y, z = blockIdx.z;
    const int tid = threadIdx.x;
    const float* src = qkv + (size_t)h * 3 * D * T + (size_t)z * D * T + tile * 64;
    __shared__ unsigned short L[4096];

    if (z == 2) {  // V: quarter-blocked [wq][c][16s], granule(4sh) swizzle g^((c>>2)&3)
        unsigned short* dst = ws + (size_t)(h * 32 + tile) * 8192 + 4096;
        const int c = tid >> 2, g = tid & 3;
        const int sg = g ^ ((c >> 2) & 3);           // source granule (s-local/4)
        #pragma unroll
        for (int wq = 0; wq < 4; wq++) {
            f32x4 a = *(const f32x4*)(src + (size_t)c * T + wq * 16 + sg * 4);
            u16x4 wv = { f2bf(a[0]), f2bf(a[1]), f2bf(a[2]), f2bf(a[3]) };
            *(u16x4*)(dst + wq * 1024 + tid * 4) = wv;   // coalesced 8B stores
        }
    } else {       // Q/K: transpose [c][t] -> swizzled [t][c] via LDS
        const float m = (z == 0) ? SCL : 1.0f;   // fold softmax scale into Q
        const int c0 = (tid >> 4) * 4, s4 = tid & 15;
        float fr[4][4];
        #pragma unroll
        for (int r = 0; r < 4; r++)
            *(f32x4*)fr[r] = *(const f32x4*)(src + (size_t)(c0 + r) * T + s4 * 4);
        #pragma unroll
        for (int j = 0; j < 4; j++) {
            int trow = s4 * 4 + j;
            u16x4 wv = { f2bf(fr[0][j] * m), f2bf(fr[1][j] * m),
                         f2bf(fr[2][j] * m), f2bf(fr[3][j] * m) };
            *(u16x4*)(L + frag_off(trow, c0) + (c0 & 7)) = wv;
        }
        __syncthreads();
        unsigned short* dst = (z == 0)
            ? ws + QP_OFF + (size_t)(h * 32 + tile) * 4096
            : ws + (size_t)(h * 32 + tile) * 8192;
        #pragma unroll
        for (int i = 0; i < 2; i++)
            *(u16x8*)(dst + tid * 16 + i * 8) = *(const u16x8*)(L + tid * 16 + i * 8);
    }
}

// ---------------- main: t-split flash attention, TQ=128, shared staging ------
// Block = 4 waves; wave w owns Q-rows {16w..16w+16} in BOTH 64-t halves of a
// 128-t Q-block (two independent t-strips per wave -> 2x ILP per staged KV
// fragment; aK/aV ds_reads amortized over both strips). KV staging identical
// to the proven R4 body: BLOCK-SHARED 16 KB/tile double-buffer, raw
// s_barrier pair per body, stage->wait distance 2, vmcnt(4).

#define STAGE(J, B)                                                          \
  { const char* g = kvb + (size_t)(J) * 16384;                               \
    char* lk = lbase + (B) * 16384;                                          \
    async_cp16(g,         lk);                                               \
    async_cp16(g + 4096,  lk + 4096);                                        \
    async_cp16(g + 8192,  lk + 8192);                                        \
    async_cp16(g + 12288, lk + 12288); }

#define BODY(KT, B, DO_STAGE, WAITIMM)                                       \
  {                                                                          \
    __builtin_amdgcn_s_waitcnt(WAITIMM);  /* own tile-KT cps landed */       \
    __builtin_amdgcn_s_barrier();         /* ALL waves' tile-KT landed */    \
    __builtin_amdgcn_sched_barrier(0);    /* no ds_read hoists above */      \
    _Pragma("unroll")                                                        \
    for (int q = 0; q < 4; q++) {                                            \
      const char* kb = sbuf + (B) * 16384 + q * 2048;                        \
      const char* vb = sbuf + (B) * 16384 + 8192 + q * 2048;                 \
      bf16x8 aK0 = *(const bf16x8*)(kb + aK0o);                              \
      bf16x8 aK1 = *(const bf16x8*)(kb + aK1o);                              \
      s16x4 aV0 = *(const s16x4*)(vb + aVo);                                 \
      s16x4 aV1 = *(const s16x4*)(vb + aVo + 512);                           \
      s16x4 aV2 = *(const s16x4*)(vb + aVo + 1024);                          \
      s16x4 aV3 = *(const s16x4*)(vb + aVo + 1536);                          \
      _Pragma("unroll")                                                      \
      for (int st = 0; st < 2; st++) {                                       \
        f32x4 s = __builtin_amdgcn_mfma_f32_16x16x32_bf16(                   \
            aK0, bQ[st][0], ZF, 0, 0, 0);                                    \
        s = __builtin_amdgcn_mfma_f32_16x16x32_bf16(aK1, bQ[st][1], s, 0,0,0);\
        float p0 = __builtin_amdgcn_exp2f(s[0]);                             \
        float p1 = __builtin_amdgcn_exp2f(s[1]);                             \
        float p2 = __builtin_amdgcn_exp2f(s[2]);                             \
        float p3 = __builtin_amdgcn_exp2f(s[3]);                             \
        l_acc[st] += (p0 + p1) + (p2 + p3);                                  \
        u32x2 pk = { pkbf(p0, p1), pkbf(p2, p3) };                           \
        s16x4 bP = __builtin_bit_cast(s16x4, pk);                            \
        acc_o[st][0] = __builtin_amdgcn_mfma_f32_16x16x16bf16_1k(            \
            aV0, bP, acc_o[st][0], 0, 0, 0);                                 \
        acc_o[st][1] = __builtin_amdgcn_mfma_f32_16x16x16bf16_1k(            \
            aV1, bP, acc_o[st][1], 0, 0, 0);                                 \
        acc_o[st][2] = __builtin_amdgcn_mfma_f32_16x16x16bf16_1k(            \
            aV2, bP, acc_o[st][2], 0, 0, 0);                                 \
        acc_o[st][3] = __builtin_amdgcn_mfma_f32_16x16x16bf16_1k(            \
            aV3, bP, acc_o[st][3], 0, 0, 0);                                 \
      }                                                                      \
    }                                                                        \
    if (DO_STAGE) {                                                          \
      __builtin_amdgcn_s_waitcnt(0xC07F);  /* lgkmcnt(0): reads done */      \
      __builtin_amdgcn_s_barrier();        /* buf (B) free to overwrite */   \
      STAGE((KT) + 2, B)                                                     \
    }                                                                        \
  }

__global__ __launch_bounds__(256, 4)
void attn_main(const unsigned short* __restrict__ ws, float* __restrict__ out) {
    const int h  = blockIdx.x;      // head pinned to XCD h%8 for L2 locality
    const int qt = blockIdx.y;      // 128-t Q-block
    const int t0 = qt * 128;
    const int tid  = threadIdx.x;
    const int lane = tid & 63;
    const int w    = tid >> 6;      // wave id = t-strip within each 64-t half
    const int ln   = lane & 15, q4 = lane >> 4;

    __shared__ char sbuf[32768];    // 2 x 16KB shared KV staging (dbuf)
    char* lbase = sbuf + w * 1024;  // this wave's staging slice (wave-uniform)

    // per-lane fragment byte offsets (quarter-local; q*2048 / ci*512 are imms)
    const int aK0o = 2 * frag_off(ln, q4 * 8);
    const int aK1o = 2 * frag_off(ln, 32 + q4 * 8);
    const int aVo  = 32 * ln + 2 * ((q4 ^ ((ln >> 2) & 3)) * 4);

    // Q fragments: rows 16w+ln of each 64-t half (two strips, 4 x 16B loads)
    const unsigned short* qtile = ws + QP_OFF + (size_t)(h * 32 + qt * 2) * 4096;
    bf16x8 bQ[2][2];
    #pragma unroll
    for (int st = 0; st < 2; st++) {
        bQ[st][0] = *(const bf16x8*)(qtile + st * 4096 + frag_off(16 * w + ln, q4 * 8));
        bQ[st][1] = *(const bf16x8*)(qtile + st * 4096 + frag_off(16 * w + ln, 32 + q4 * 8));
    }

    const char* kvb = (const char*)ws + (size_t)(h * 32) * 16384
                      + w * 1024 + lane * 16;
    STAGE(0, 0)                      // tiles 0,1 in flight (8 cps)
    STAGE(1, 1)

    const f32x4 ZF = {0.f, 0.f, 0.f, 0.f};
    f32x4 acc_o[2][4];   // [strip][ci]: O rows c=16ci+q4*4+rr, col t=ln
    #pragma unroll
    for (int st = 0; st < 2; st++)
        #pragma unroll
        for (int ci = 0; ci < 4; ci++) acc_o[st][ci] = ZF;
    float l_acc[2] = {0.f, 0.f};

    #pragma unroll 1
    for (int m = 0; m < 15; m++) {   // kt = 0..29
        BODY(2 * m,     0, 1, 0x0F74)   // vmcnt(4)
        BODY(2 * m + 1, 1, 1, 0x0F74)
    }
    BODY(30, 0, 0, 0x0F74)           // no stage; tile 31 still in flight
    BODY(31, 1, 0, 0x0F70)           // vmcnt(0)

    // ---- epilogue: l over q4 groups, direct store (no LDS, no merge) ----
    #pragma unroll
    for (int st = 0; st < 2; st++) {
        float sl = l_acc[st];
        sl += __shfl_xor(sl, 16, 64);
        sl += __shfl_xor(sl, 32, 64);
        const float linv = 1.0f / sl;
        float* ob = out + (size_t)h * D * T + t0 + st * 64 + 16 * w + ln;
        #pragma unroll
        for (int ci = 0; ci < 4; ci++)
            #pragma unroll
            for (int rr = 0; rr < 4; rr++)
                ob[(size_t)(16 * ci + q4 * 4 + rr) * T] = acc_o[st][ci][rr] * linv;
    }
}

// ---------------- fallback (proven): used if ws too small --------------------
__device__ inline bf16x8 frag8(const unsigned short* p, int row, int c0) {
    return *(const bf16x8*)(p + frag_off(row, c0));
}

__global__ __launch_bounds__(256)
void attn_fallback(const float* __restrict__ qkv, float* __restrict__ out) {
    const int h     = blockIdx.y;
    const int t0    = blockIdx.x * 64;
    const int tid   = threadIdx.x;
    const int lane  = tid & 63;
    const int strip = tid >> 6;
    const int ln    = lane & 15;
    const int q4    = lane >> 4;

    __shared__ unsigned short Qs[64 * D];
    __shared__ unsigned short Ks[64 * D];
    __shared__ unsigned short Vs[D * 64];
    __shared__ unsigned short Pss[64 * 64];
    __shared__ float l_lds[64];

    const float* qb = qkv + (size_t)h * 3 * D * T;
    const float* kb = qb + (size_t)D * T;
    const float* vb = qb + (size_t)(2 * D) * T;
    const int s4 = tid & 15;
    const int c0 = (tid >> 4) * 4;
    {
        float fr[4][4];
        #pragma unroll
        for (int r = 0; r < 4; r++)
            *(f32x4*)fr[r] = *(const f32x4*)(qb + (size_t)(c0 + r) * T + t0 + s4 * 4);
        #pragma unroll
        for (int j = 0; j < 4; j++) {
            int trow = s4 * 4 + j;
            u16x4 wv = { f2bf(fr[0][j]), f2bf(fr[1][j]), f2bf(fr[2][j]), f2bf(fr[3][j]) };
            *(u16x4*)(Qs + frag_off(trow, c0) + (c0 & 7)) = wv;
        }
    }
    __syncthreads();
    const int arow = strip * 16 + ln;
    const int kg   = q4 * 8;
    const bf16x8 aq0 = frag8(Qs, arow, kg);
    const bf16x8 aq1 = frag8(Qs, arow, 32 + kg);
    f32x4 acc_o[4];
    #pragma unroll
    for (int m = 0; m < 4; m++) acc_o[m] = (f32x4){0.f, 0.f, 0.f, 0.f};
    float l_acc[4] = {0.f, 0.f, 0.f, 0.f};
    constexpr float S2 = 0.125f * 1.44269504088896340736f;
    for (int kt = 0; kt < NT; kt++) {
        const int s0 = kt * 64;
        float kr[4][4], vr[4][4];
        #pragma unroll
        for (int r = 0; r < 4; r++)
            *(f32x4*)kr[r] = *(const f32x4*)(kb + (size_t)(c0 + r) * T + s0 + s4 * 4);
        #pragma unroll
        for (int r = 0; r < 4; r++)
            *(f32x4*)vr[r] = *(const f32x4*)(vb + (size_t)(c0 + r) * T + s0 + s4 * 4);
        __syncthreads();
        #pragma unroll
        for (int j = 0; j < 4; j++) {
            int srow = s4 * 4 + j;
            u16x4 wk = { f2bf(kr[0][j]), f2bf(kr[1][j]), f2bf(kr[2][j]), f2bf(kr[3][j]) };
            *(u16x4*)(Ks + frag_off(srow, c0) + (c0 & 7)) = wk;
        }
        #pragma unroll
        for (int r = 0; r < 4; r++) {
            int row = c0 + r, cc = s4 * 4;
            u16x4 wv = { f2bf(vr[r][0]), f2bf(vr[r][1]), f2bf(vr[r][2]), f2bf(vr[r][3]) };
            *(u16x4*)(Vs + frag_off(row, cc) + (cc & 7)) = wv;
        }
        __syncthreads();
        f32x4 accs[4];
        #pragma unroll
        for (int ns = 0; ns < 4; ns++) {
            bf16x8 b0 = frag8(Ks, ns * 16 + ln, kg);
            bf16x8 b1 = frag8(Ks, ns * 16 + ln, 32 + kg);
            f32x4 z = {0.f, 0.f, 0.f, 0.f};
            z = __builtin_amdgcn_mfma_f32_16x16x32_bf16(aq0, b0, z, 0, 0, 0);
            z = __builtin_amdgcn_mfma_f32_16x16x32_bf16(aq1, b1, z, 0, 0, 0);
            accs[ns] = z;
        }
        #pragma unroll
        for (int ns = 0; ns < 4; ns++) {
            int scol = ns * 16 + ln;
            #pragma unroll
            for (int r = 0; r < 4; r++) {
                float p = __builtin_amdgcn_exp2f(accs[ns][r] * S2);
                l_acc[r] += p;
                int trow = strip * 16 + q4 * 4 + r;
                int g = ((scol >> 3) ^ ((trow >> 1) & 7));
                Pss[trow * 64 + g * 8 + (scol & 7)] = f2bf(p);
            }
        }
        bf16x8 bp0 = frag8(Pss, arow, kg);
        bf16x8 bp1 = frag8(Pss, arow, 32 + kg);
        #pragma unroll
        for (int ms = 0; ms < 4; ms++) {
            bf16x8 av0 = frag8(Vs, ms * 16 + ln, kg);
            bf16x8 av1 = frag8(Vs, ms * 16 + ln, 32 + kg);
            acc_o[ms] = __builtin_amdgcn_mfma_f32_16x16x32_bf16(av0, bp0, acc_o[ms], 0, 0, 0);
            acc_o[ms] = __builtin_amdgcn_mfma_f32_16x16x32_bf16(av1, bp1, acc_o[ms], 0, 0, 0);
        }
    }
    #pragma unroll
    for (int r = 0; r < 4; r++) {
        float s = l_acc[r];
        s += __shfl_xor(s, 1, 64);
        s += __shfl_xor(s, 2, 64);
        s += __shfl_xor(s, 4, 64);
        s += __shfl_xor(s, 8, 64);
        if (ln == 0) l_lds[strip * 16 + q4 * 4 + r] = s;
    }
    const float linv = 1.0f / l_lds[strip * 16 + ln];
    const int tg = t0 + strip * 16 + ln;
    float* ob = out + (size_t)h * D * T;
    #pragma unroll
    for (int ms = 0; ms < 4; ms++)
        #pragma unroll
        for (int r = 0; r < 4; r++) {
            int c = ms * 16 + q4 * 4 + r;
            ob[(size_t)c * T + tg] = acc_o[ms][r] * linv;
        }
}

} // namespace

extern "C" void kernel_launch(void* const* d_in, const int* in_sizes, int n_in,
                              void* d_out, int out_size, void* d_ws, size_t ws_size,
                              hipStream_t stream) {
    const float* qkv = (const float*)d_in[0];
    float* out = (float*)d_out;
    if (ws_size >= WS_NEED) {
        prepass<<<dim3(32, 64, 3), 256, 0, stream>>>(qkv, (unsigned short*)d_ws);
        attn_main<<<dim3(64, 16), 256, 0, stream>>>((const unsigned short*)d_ws, out);
    } else {
        attn_fallback<<<dim3(32, 64), 256, 0, stream>>>(qkv, out);
    }
}